// Round 1
// baseline (49718.497 us; speedup 1.0000x reference)
//
#include <hip/hip_runtime.h>
#include <math.h>

#define B_   8
#define S_   64
#define N_   100
#define D_   1024
#define ND_  768
#define BN_  800
#define G3_  3072
#define TM   32
#define TN   128
#define NB_EPRE 32

static __device__ __forceinline__ float wave_sum(float v) {
    for (int off = 32; off > 0; off >>= 1) v += __shfl_down(v, off, 64);
    return v;
}

// All 256 threads must call; returns full-block sum to every thread.
static __device__ __forceinline__ float block_sum(float v) {
    __shared__ float red_[8];
    float w = wave_sum(v);
    int lane = threadIdx.x & 63, wid = threadIdx.x >> 6;
    __syncthreads();               // protect red_ reuse across calls
    if (lane == 0) red_[wid] = w;
    __syncthreads();
    float t = 0.f;
    for (int i = 0; i < 4; ++i) t += red_[i];
    return t;
}

static __device__ __forceinline__ float gelu_f(float x) {
    return 0.5f * x * (1.f + erff(x * 0.70710678118654752f));
}

// ---------------------------------------------------------------------------
// Generic tiled GEMM: C[M,Nc] = A[M,K] @ W[Nc,K]^T (+bias). K%32==0, Nc%TN==0.
// ---------------------------------------------------------------------------
__global__ __launch_bounds__(256) void gemm_wt(
    const float* __restrict__ A, const float* __restrict__ Wm,
    const float* __restrict__ bias, float* __restrict__ C,
    int M, int Nc, int K)
{
    __shared__ float sA[TM][33];
    __shared__ float sW[TN][33];
    int m0 = blockIdx.y * TM, n0 = blockIdx.x * TN;
    if (m0 >= M) return;
    int tid = threadIdx.x;
    int ty = tid >> 4, tx = tid & 15;
    int rr = tid >> 3, kc = (tid & 7) * 4;
    float acc[2][8] = {};
    for (int k0 = 0; k0 < K; k0 += 32) {
        {
            int gm = m0 + rr;
            float4 v = make_float4(0.f, 0.f, 0.f, 0.f);
            if (gm < M) v = *(const float4*)(A + (size_t)gm * K + k0 + kc);
            sA[rr][kc] = v.x; sA[rr][kc+1] = v.y; sA[rr][kc+2] = v.z; sA[rr][kc+3] = v.w;
        }
        for (int q = 0; q < 4; ++q) {
            int cc = rr + q * 32;
            float4 v = *(const float4*)(Wm + (size_t)(n0 + cc) * K + k0 + kc);
            sW[cc][kc] = v.x; sW[cc][kc+1] = v.y; sW[cc][kc+2] = v.z; sW[cc][kc+3] = v.w;
        }
        __syncthreads();
#pragma unroll
        for (int kk = 0; kk < 32; ++kk) {
            float a0 = sA[ty*2][kk], a1 = sA[ty*2+1][kk];
#pragma unroll
            for (int j = 0; j < 8; ++j) {
                float w = sW[tx + 16*j][kk];
                acc[0][j] += a0 * w;
                acc[1][j] += a1 * w;
            }
        }
        __syncthreads();
    }
    for (int i = 0; i < 2; ++i) {
        int gm = m0 + ty*2 + i;
        if (gm < M) {
            for (int j = 0; j < 8; ++j) {
                int d = n0 + tx + 16*j;
                float bv = bias ? bias[d] : 0.f;
                C[(size_t)gm * Nc + d] = acc[i][j] + bv;
            }
        }
    }
}

// ---------------------------------------------------------------------------
// h0 = mask * (type_embed[type] + LN(P, name_ln))
// ---------------------------------------------------------------------------
__global__ __launch_bounds__(256) void k_h0(
    const float* __restrict__ P, const int* __restrict__ etype,
    const int* __restrict__ emask, const float* __restrict__ temb,
    const float* __restrict__ g, const float* __restrict__ bt,
    float* __restrict__ h)
{
    int bn = blockIdx.x, tid = threadIdx.x;
    int t = etype[bn], mk = emask[bn];
    float x[4]; float lsum = 0.f;
    for (int k = 0; k < 4; ++k) { x[k] = P[(size_t)bn*D_ + tid + 256*k]; lsum += x[k]; }
    float mean = block_sum(lsum) * (1.f / D_);
    float lv = 0.f;
    for (int k = 0; k < 4; ++k) { float d = x[k] - mean; lv += d * d; }
    float inv = rsqrtf(block_sum(lv) * (1.f / D_) + 1e-5f);
    for (int k = 0; k < 4; ++k) {
        int d = tid + 256*k;
        float y = (x[k] - mean) * inv * g[d] + bt[d];
        h[(size_t)bn*D_ + d] = mk ? (temb[(size_t)t*D_ + d] + y) : 0.f;
    }
}

// ---------------------------------------------------------------------------
// Step A: roles, wsum, mean_ent (per b); zero compaction counter.
// ---------------------------------------------------------------------------
__global__ __launch_bounds__(256) void k_step_a(
    const float* __restrict__ inc, const int* __restrict__ emask,
    const float* __restrict__ h, float* __restrict__ roles,
    float* __restrict__ mean_ent, int* __restrict__ cnt, int s)
{
    int b = blockIdx.x, tid = threadIdx.x;
    __shared__ float sroles[N_];
    float r = 0.f;
    if (tid < N_) {
        float iv = inc[((size_t)b*N_ + tid)*S_ + s];
        r = emask[b*N_ + tid] ? iv : 0.f;
        sroles[tid] = r;
        roles[b*N_ + tid] = r;
    }
    float tot = block_sum(r);           // also orders sroles stores
    if (tid == 0 && b == 0) *cnt = 0;
    float inv = 1.f / fmaxf(tot, 1.f);
    for (int d = tid; d < D_; d += 256) {
        float acc = 0.f;
        for (int n = 0; n < N_; ++n) acc += sroles[n] * h[((size_t)b*N_ + n)*D_ + d];
        mean_ent[b*D_ + d] = acc * inv;
    }
}

// ---------------------------------------------------------------------------
// Step B: blocks [0,32): e_pre = n2e(mean_ent)+t2e(x_s)+biases (pre-LN)
//         blocks [32,832): per-(b,n) arc/int contexts + active compaction
// ---------------------------------------------------------------------------
__global__ __launch_bounds__(256) void k_step_b(
    const float* __restrict__ scene, const float* __restrict__ inc,
    const float* __restrict__ h, const float* __restrict__ esbuf,
    const float* __restrict__ n2eW, const float* __restrict__ n2eb,
    const float* __restrict__ t2eW, const float* __restrict__ t2eb,
    const float* __restrict__ roles, const float* __restrict__ mean_ent,
    float* __restrict__ e_pre, float* __restrict__ ctxa, float* __restrict__ ctxi,
    int* __restrict__ cnt, int* __restrict__ list, float* __restrict__ rowrole,
    int s)
{
    int tid = threadIdx.x;
    if (blockIdx.x < NB_EPRE) {
        __shared__ float sme[B_][D_ + 4];
        __shared__ float sxs[B_][D_ + 4];
        for (int i = tid; i < B_*D_; i += 256) {
            int b2 = i >> 10, j = i & (D_ - 1);
            sme[b2][j] = mean_ent[i];
            sxs[b2][j] = scene[((size_t)b2*S_ + s)*D_ + j];
        }
        __syncthreads();
        int il = tid >> 3, b = tid & 7;
        int i = blockIdx.x * 32 + il;
        float acc = n2eb[i] + t2eb[i];
        const float* wn = n2eW + (size_t)i * D_;
        const float* wt = t2eW + (size_t)i * D_;
        for (int j = 0; j < D_; j += 4) {
            float4 a = *(const float4*)(wn + j);
            float4 c = *(const float4*)(wt + j);
            acc += a.x*sme[b][j] + a.y*sme[b][j+1] + a.z*sme[b][j+2] + a.w*sme[b][j+3];
            acc += c.x*sxs[b][j] + c.y*sxs[b][j+1] + c.z*sxs[b][j+2] + c.w*sxs[b][j+3];
        }
        e_pre[b*D_ + i] = acc;
    } else {
        int m = blockIdx.x - NB_EPRE;
        int b = m / N_, n = m - b * N_;
        float r = roles[m];
        if (r <= 0.f) return;
        __shared__ int sidx, nwa, nwi;
        __shared__ float wav[S_]; __shared__ int wai[S_];
        __shared__ float wiv[N_]; __shared__ int wii[N_];
        if (tid == 0) { sidx = atomicAdd(cnt, 1); nwa = 0; nwi = 0; }
        __syncthreads();
        int idx = sidx;
        if (tid == 0) { list[idx] = m; rowrole[idx] = r; }
        float wa = 0.f;
        if (tid < s) {
            float denom = fmaxf((float)(s - 1), 1.f);
            float iv = inc[(size_t)m*S_ + tid];
            if (iv > 0.f) {
                wa = iv * r * expf(-1.f + (float)tid / denom);
                int p = atomicAdd(&nwa, 1);
                wav[p] = wa; wai[p] = tid;
            }
        }
        float denA = block_sum(wa);
        float wi = 0.f;
        if (tid < N_ && tid != n) {
            float rm = roles[b*N_ + tid];
            if (rm > 0.f) {
                wi = r * rm;
                int p = atomicAdd(&nwi, 1);
                wiv[p] = wi; wii[p] = tid;
            }
        }
        float denI = block_sum(wi);
        __syncthreads();
        float sclA = 1.f / fmaxf(denA, 1e-8f);
        float sclI = 1.f / fmaxf(denI, 1e-8f);
        int na = nwa, ni = nwi;
        for (int d = tid; d < D_; d += 256) {
            float a = 0.f;
            for (int j = 0; j < na; ++j) a += wav[j] * esbuf[((size_t)b*S_ + wai[j])*D_ + d];
            ctxa[(size_t)idx*D_ + d] = a * sclA;
            float c = 0.f;
            for (int j = 0; j < ni; ++j) c += wiv[j] * h[((size_t)b*N_ + wii[j])*D_ + d];
            ctxi[(size_t)idx*D_ + d] = c * sclI;
        }
    }
}

// ---------------------------------------------------------------------------
// Step C: e_s = LN(e_pre) -> esbuf[b,s,:]; gate[b,0..2] via softmax(MLP(e_s))
// ---------------------------------------------------------------------------
__global__ __launch_bounds__(256) void k_step_c(
    const float* __restrict__ e_pre, const float* __restrict__ elng, const float* __restrict__ elnb,
    const float* __restrict__ gW1, const float* __restrict__ gb1,
    const float* __restrict__ gW2, const float* __restrict__ gb2,
    float* __restrict__ esbuf, float* __restrict__ gate, int s)
{
    int b = blockIdx.x, tid = threadIdx.x;
    __shared__ float se[D_];
    float x[4]; float lsum = 0.f;
    for (int k = 0; k < 4; ++k) { x[k] = e_pre[b*D_ + tid + 256*k]; lsum += x[k]; }
    float mean = block_sum(lsum) * (1.f / D_);
    float lv = 0.f;
    for (int k = 0; k < 4; ++k) { float d = x[k] - mean; lv += d * d; }
    float inv = rsqrtf(block_sum(lv) * (1.f / D_) + 1e-5f);
    for (int k = 0; k < 4; ++k) {
        int d = tid + 256*k;
        float y = (x[k] - mean) * inv * elng[d] + elnb[d];
        se[d] = y;
        esbuf[((size_t)b*S_ + s)*D_ + d] = y;
    }
    __syncthreads();
    float acc = gb1[tid];
    const float* w1 = gW1 + (size_t)tid * D_;
    for (int j = 0; j < D_; j += 4) {
        float4 w = *(const float4*)(w1 + j);
        acc += w.x*se[j] + w.y*se[j+1] + w.z*se[j+2] + w.w*se[j+3];
    }
    float hg = gelu_f(acc);
    __shared__ float sh[256];
    sh[tid] = hg;
    float g[3];
    for (int c = 0; c < 3; ++c)
        g[c] = block_sum(gW2[c*256 + tid] * sh[tid]) + gb2[c];
    float mx = fmaxf(g[0], fmaxf(g[1], g[2]));
    float e0 = expf(g[0]-mx), e1 = expf(g[1]-mx), e2 = expf(g[2]-mx);
    float si = 1.f / (e0 + e1 + e2);
    if (tid == 0) { gate[b*4+0] = e0*si; gate[b*4+1] = e1*si; gate[b*4+2] = e2*si; }
}

// ---------------------------------------------------------------------------
// Step D: fused triple GEMM -> msg (compact rows).
// msg = g0*(ms_W e_s + ms_b) + g1*act*(ma_W ctxa + ma_b) + g2*(mi_W ctxi + mi_b) + r*role_w
// Gate coefs pre-scaled into A rows; biases in epilogue.
// ---------------------------------------------------------------------------
__global__ __launch_bounds__(256) void k_msg_gemm(
    const float* __restrict__ ctxa, const float* __restrict__ ctxi,
    const float* __restrict__ esbuf, const float* __restrict__ gate,
    const int* __restrict__ list, const int* __restrict__ cnt,
    const float* __restrict__ rowrole,
    const float* __restrict__ maW, const float* __restrict__ miW, const float* __restrict__ msW,
    const float* __restrict__ maB, const float* __restrict__ miB, const float* __restrict__ msB,
    const float* __restrict__ rolew, float* __restrict__ msg, int s)
{
    int M = *cnt;
    int m0 = blockIdx.y * TM;
    if (m0 >= M) return;
    int n0 = blockIdx.x * TN;
    int tid = threadIdx.x;
    __shared__ float sAa[TM][33], sAi[TM][33], sAs[TM][33];
    __shared__ float sWa[TN][33], sWi[TN][33], sWs[TN][33];
    __shared__ float sg0[TM], sg1[TM], sg2[TM], srr[TM];
    __shared__ int sb[TM];
    if (tid < TM) {
        int gm = m0 + tid;
        float g0 = 0.f, g1 = 0.f, g2 = 0.f, rv = 0.f; int b = 0;
        if (gm < M) {
            int bn = list[gm]; b = bn / N_;
            g0 = gate[b*4];
            g1 = (s > 0) ? gate[b*4+1] : 0.f;
            g2 = gate[b*4+2];
            rv = rowrole[gm];
        }
        sg0[tid] = g0; sg1[tid] = g1; sg2[tid] = g2; srr[tid] = rv; sb[tid] = b;
    }
    __syncthreads();
    int ty = tid >> 4, tx = tid & 15;
    int rr = tid >> 3, kc = (tid & 7) * 4;
    float acc[2][8] = {};
    for (int k0 = 0; k0 < D_; k0 += 32) {
        {
            int gm = m0 + rr;
            float4 va = make_float4(0.f,0.f,0.f,0.f), vi = va, vs = va;
            if (gm < M) {
                va = *(const float4*)(ctxa + (size_t)gm*D_ + k0 + kc);
                vi = *(const float4*)(ctxi + (size_t)gm*D_ + k0 + kc);
                vs = *(const float4*)(esbuf + ((size_t)sb[rr]*S_ + s)*D_ + k0 + kc);
                float g1v = sg1[rr], g2v = sg2[rr], g0v = sg0[rr];
                va.x *= g1v; va.y *= g1v; va.z *= g1v; va.w *= g1v;
                vi.x *= g2v; vi.y *= g2v; vi.z *= g2v; vi.w *= g2v;
                vs.x *= g0v; vs.y *= g0v; vs.z *= g0v; vs.w *= g0v;
            }
            sAa[rr][kc] = va.x; sAa[rr][kc+1] = va.y; sAa[rr][kc+2] = va.z; sAa[rr][kc+3] = va.w;
            sAi[rr][kc] = vi.x; sAi[rr][kc+1] = vi.y; sAi[rr][kc+2] = vi.z; sAi[rr][kc+3] = vi.w;
            sAs[rr][kc] = vs.x; sAs[rr][kc+1] = vs.y; sAs[rr][kc+2] = vs.z; sAs[rr][kc+3] = vs.w;
        }
        for (int q = 0; q < 4; ++q) {
            int cc = rr + q * 32;
            float4 wa = *(const float4*)(maW + (size_t)(n0+cc)*D_ + k0 + kc);
            float4 wi = *(const float4*)(miW + (size_t)(n0+cc)*D_ + k0 + kc);
            float4 ws = *(const float4*)(msW + (size_t)(n0+cc)*D_ + k0 + kc);
            sWa[cc][kc] = wa.x; sWa[cc][kc+1] = wa.y; sWa[cc][kc+2] = wa.z; sWa[cc][kc+3] = wa.w;
            sWi[cc][kc] = wi.x; sWi[cc][kc+1] = wi.y; sWi[cc][kc+2] = wi.z; sWi[cc][kc+3] = wi.w;
            sWs[cc][kc] = ws.x; sWs[cc][kc+1] = ws.y; sWs[cc][kc+2] = ws.z; sWs[cc][kc+3] = ws.w;
        }
        __syncthreads();
#pragma unroll
        for (int kk = 0; kk < 32; ++kk) {
            float a0a = sAa[ty*2][kk],  a1a = sAa[ty*2+1][kk];
            float a0i = sAi[ty*2][kk],  a1i = sAi[ty*2+1][kk];
            float a0s = sAs[ty*2][kk],  a1s = sAs[ty*2+1][kk];
#pragma unroll
            for (int j = 0; j < 8; ++j) {
                int c = tx + 16*j;
                float wa = sWa[c][kk], wi = sWi[c][kk], ws = sWs[c][kk];
                acc[0][j] += a0a*wa + a0i*wi + a0s*ws;
                acc[1][j] += a1a*wa + a1i*wi + a1s*ws;
            }
        }
        __syncthreads();
    }
    for (int i = 0; i < 2; ++i) {
        int r2 = ty*2 + i;
        int gm = m0 + r2;
        if (gm < M) {
            float g0 = sg0[r2], g1 = sg1[r2], g2 = sg2[r2], rv = srr[r2];
            for (int j = 0; j < 8; ++j) {
                int d = n0 + tx + 16*j;
                msg[(size_t)gm*D_ + d] = acc[i][j] + g0*msB[d] + g1*maB[d] + g2*miB[d] + rv*rolew[d];
            }
        }
    }
}

// ---------------------------------------------------------------------------
// Step E: dual GEMM gi = msg@Wih^T+bih, gh = h@Whh^T+bhh (compact rows).
// ---------------------------------------------------------------------------
__global__ __launch_bounds__(256) void k_gru_gemm(
    const float* __restrict__ msg, const float* __restrict__ h,
    const int* __restrict__ list, const int* __restrict__ cnt,
    const float* __restrict__ Wih, const float* __restrict__ Whh,
    const float* __restrict__ bih, const float* __restrict__ bhh,
    float* __restrict__ gi, float* __restrict__ gh)
{
    int M = *cnt;
    int m0 = blockIdx.y * TM;
    if (m0 >= M) return;
    int n0 = blockIdx.x * TN;
    int tid = threadIdx.x;
    __shared__ float sAm[TM][33], sAh[TM][33];
    __shared__ float sWi[TN][33], sWh[TN][33];
    __shared__ int slist[TM];
    if (tid < TM) {
        int gm = m0 + tid;
        slist[tid] = (gm < M) ? list[gm] : 0;
    }
    __syncthreads();
    int ty = tid >> 4, tx = tid & 15;
    int rr = tid >> 3, kc = (tid & 7) * 4;
    float ai[2][8] = {}, ah[2][8] = {};
    for (int k0 = 0; k0 < D_; k0 += 32) {
        {
            int gm = m0 + rr;
            float4 vm = make_float4(0.f,0.f,0.f,0.f), vh = vm;
            if (gm < M) {
                vm = *(const float4*)(msg + (size_t)gm*D_ + k0 + kc);
                vh = *(const float4*)(h + (size_t)slist[rr]*D_ + k0 + kc);
            }
            sAm[rr][kc] = vm.x; sAm[rr][kc+1] = vm.y; sAm[rr][kc+2] = vm.z; sAm[rr][kc+3] = vm.w;
            sAh[rr][kc] = vh.x; sAh[rr][kc+1] = vh.y; sAh[rr][kc+2] = vh.z; sAh[rr][kc+3] = vh.w;
        }
        for (int q = 0; q < 4; ++q) {
            int cc = rr + q * 32;
            float4 wi = *(const float4*)(Wih + (size_t)(n0+cc)*D_ + k0 + kc);
            float4 wh = *(const float4*)(Whh + (size_t)(n0+cc)*D_ + k0 + kc);
            sWi[cc][kc] = wi.x; sWi[cc][kc+1] = wi.y; sWi[cc][kc+2] = wi.z; sWi[cc][kc+3] = wi.w;
            sWh[cc][kc] = wh.x; sWh[cc][kc+1] = wh.y; sWh[cc][kc+2] = wh.z; sWh[cc][kc+3] = wh.w;
        }
        __syncthreads();
#pragma unroll
        for (int kk = 0; kk < 32; ++kk) {
            float a0m = sAm[ty*2][kk], a1m = sAm[ty*2+1][kk];
            float a0h = sAh[ty*2][kk], a1h = sAh[ty*2+1][kk];
#pragma unroll
            for (int j = 0; j < 8; ++j) {
                int c = tx + 16*j;
                float wi = sWi[c][kk], wh = sWh[c][kk];
                ai[0][j] += a0m*wi; ai[1][j] += a1m*wi;
                ah[0][j] += a0h*wh; ah[1][j] += a1h*wh;
            }
        }
        __syncthreads();
    }
    for (int i = 0; i < 2; ++i) {
        int gm = m0 + ty*2 + i;
        if (gm < M) {
            for (int j = 0; j < 8; ++j) {
                int d = n0 + tx + 16*j;
                gi[(size_t)gm*G3_ + d] = ai[i][j] + bih[d];
                gh[(size_t)gm*G3_ + d] = ah[i][j] + bhh[d];
            }
        }
    }
}

// ---------------------------------------------------------------------------
// Step F: GRU gates + LN + clip, masked write into h (active rows only).
// ---------------------------------------------------------------------------
__global__ __launch_bounds__(256) void k_gru_fin(
    const float* __restrict__ gi, const float* __restrict__ gh,
    const int* __restrict__ list, const int* __restrict__ cnt,
    const float* __restrict__ ulng, const float* __restrict__ ulnb,
    float* __restrict__ h)
{
    int row = blockIdx.x;
    if (row >= *cnt) return;
    int bn = list[row];
    int tid = threadIdx.x;
    float u[4]; float lsum = 0.f;
    for (int k = 0; k < 4; ++k) {
        int d = tid + 256*k;
        float ir = gi[(size_t)row*G3_ + d];
        float iz = gi[(size_t)row*G3_ + D_ + d];
        float in_ = gi[(size_t)row*G3_ + 2*D_ + d];
        float hr = gh[(size_t)row*G3_ + d];
        float hz = gh[(size_t)row*G3_ + D_ + d];
        float hn = gh[(size_t)row*G3_ + 2*D_ + d];
        float hv = h[(size_t)bn*D_ + d];
        float r = 1.f / (1.f + expf(-(ir + hr)));
        float z = 1.f / (1.f + expf(-(iz + hz)));
        float nn = tanhf(in_ + r * hn);
        u[k] = (1.f - z) * nn + z * hv;
        lsum += u[k];
    }
    float mean = block_sum(lsum) * (1.f / D_);
    float lv = 0.f;
    for (int k = 0; k < 4; ++k) { float d = u[k] - mean; lv += d * d; }
    float inv = rsqrtf(block_sum(lv) * (1.f / D_) + 1e-5f);
    for (int k = 0; k < 4; ++k) {
        int d = tid + 256*k;
        float y = (u[k] - mean) * inv * ulng[d] + ulnb[d];
        y = fminf(fmaxf(y, -50.f), 50.f);
        h[(size_t)bn*D_ + d] = y;
    }
}

// ---------------------------------------------------------------------------
// Final: buf = LN(buf + scene, res_ln)   (in-place per row)
// ---------------------------------------------------------------------------
__global__ __launch_bounds__(256) void k_resln(
    float* __restrict__ buf, const float* __restrict__ scene,
    const float* __restrict__ g, const float* __restrict__ bt)
{
    size_t row = blockIdx.x;
    int tid = threadIdx.x;
    float x[4]; float lsum = 0.f;
    for (int k = 0; k < 4; ++k) {
        int d = tid + 256*k;
        x[k] = buf[row*D_ + d] + scene[row*D_ + d];
        lsum += x[k];
    }
    float mean = block_sum(lsum) * (1.f / D_);
    float lv = 0.f;
    for (int k = 0; k < 4; ++k) { float d = x[k] - mean; lv += d * d; }
    float inv = rsqrtf(block_sum(lv) * (1.f / D_) + 1e-5f);
    for (int k = 0; k < 4; ++k) {
        int d = tid + 256*k;
        buf[row*D_ + d] = (x[k] - mean) * inv * g[d] + bt[d];
    }
}

// ---------------------------------------------------------------------------
// Final: H = LN(gelu(G), eo_ln); plus h_fin copy blocks.
// ---------------------------------------------------------------------------
__global__ __launch_bounds__(256) void k_final(
    const float* __restrict__ G, const float* __restrict__ g, const float* __restrict__ bt,
    float* __restrict__ outH, const float* __restrict__ h, float* __restrict__ outh)
{
    int tid = threadIdx.x;
    if (blockIdx.x < B_*S_) {
        size_t row = blockIdx.x;
        float x[4]; float lsum = 0.f;
        for (int k = 0; k < 4; ++k) {
            x[k] = gelu_f(G[row*D_ + tid + 256*k]);
            lsum += x[k];
        }
        float mean = block_sum(lsum) * (1.f / D_);
        float lv = 0.f;
        for (int k = 0; k < 4; ++k) { float d = x[k] - mean; lv += d * d; }
        float inv = rsqrtf(block_sum(lv) * (1.f / D_) + 1e-5f);
        for (int k = 0; k < 4; ++k) {
            int d = tid + 256*k;
            outH[row*D_ + d] = (x[k] - mean) * inv * g[d] + bt[d];
        }
    } else {
        size_t bn = blockIdx.x - B_*S_;
        for (int d = tid; d < D_; d += 256)
            outh[bn*D_ + d] = h[bn*D_ + d];
    }
}

// ---------------------------------------------------------------------------
extern "C" void kernel_launch(void* const* d_in, const int* in_sizes, int n_in,
                              void* d_out, int out_size, void* d_ws, size_t ws_size,
                              hipStream_t stream)
{
    const float* scene = (const float*)d_in[0];
    const float* inc   = (const float*)d_in[1];
    const int*   etype = (const int*)d_in[3];
    const int*   emask = (const int*)d_in[4];
    const float* nemb  = (const float*)d_in[5];
    const float* temb  = (const float*)d_in[6];
    const float* nameW = (const float*)d_in[7];
    const float* nlg   = (const float*)d_in[8];
    const float* nlb   = (const float*)d_in[9];
    const float* n2eW  = (const float*)d_in[10];
    const float* n2eb  = (const float*)d_in[11];
    const float* t2eW  = (const float*)d_in[12];
    const float* t2eb  = (const float*)d_in[13];
    const float* elng  = (const float*)d_in[14];
    const float* elnb  = (const float*)d_in[15];
    const float* gW1   = (const float*)d_in[16];
    const float* gb1   = (const float*)d_in[17];
    const float* gW2   = (const float*)d_in[18];
    const float* gb2   = (const float*)d_in[19];
    const float* msW   = (const float*)d_in[20];
    const float* msB   = (const float*)d_in[21];
    const float* maW   = (const float*)d_in[22];
    const float* maB   = (const float*)d_in[23];
    const float* miW   = (const float*)d_in[24];
    const float* miB   = (const float*)d_in[25];
    const float* rolew = (const float*)d_in[26];
    const float* Wih   = (const float*)d_in[27];
    const float* Whh   = (const float*)d_in[28];
    const float* bih   = (const float*)d_in[29];
    const float* bhh   = (const float*)d_in[30];
    const float* ulng  = (const float*)d_in[31];
    const float* ulnb  = (const float*)d_in[32];
    const float* eoW   = (const float*)d_in[33];
    const float* eoB   = (const float*)d_in[34];
    const float* eolng = (const float*)d_in[35];
    const float* eolnb = (const float*)d_in[36];
    const float* rlng  = (const float*)d_in[37];
    const float* rlnb  = (const float*)d_in[38];

    float* outH = (float*)d_out;                    // [B,S,D] — doubles as ebuf (es history)
    float* outh = outH + (size_t)B_*S_*D_;          // [B,N,D] h_fin

    float* W = (float*)d_ws;
    size_t o = 0;
    float* roles    = W + o; o += BN_;
    float* mean_ent = W + o; o += (size_t)B_*D_;
    float* e_pre    = W + o; o += (size_t)B_*D_;
    float* gatep    = W + o; o += B_*4;
    float* rowrole  = W + o; o += BN_;
    float* ctxa     = W + o; o += (size_t)BN_*D_;
    float* ctxi     = W + o; o += (size_t)BN_*D_;
    float* msgb     = W + o; o += (size_t)BN_*D_;   // also P (init) and G (final)
    float* hbuf     = W + o; o += (size_t)BN_*D_;
    float* gi       = W + o; o += (size_t)BN_*G3_;
    float* gh       = W + o; o += (size_t)BN_*G3_;
    int*   cnt      = (int*)(W + o); o += 1;
    int*   list     = (int*)(W + o); o += BN_;

    const int MT = (BN_ + TM - 1) / TM;  // 25

    // init: P = name_embs @ name_W^T ; h0
    gemm_wt<<<dim3(D_/TN, MT), 256, 0, stream>>>(nemb, nameW, nullptr, msgb, BN_, D_, ND_);
    k_h0<<<BN_, 256, 0, stream>>>(msgb, etype, emask, temb, nlg, nlb, hbuf);

    for (int s = 0; s < S_; ++s) {
        k_step_a<<<B_, 256, 0, stream>>>(inc, emask, hbuf, roles, mean_ent, cnt, s);
        k_step_b<<<NB_EPRE + BN_, 256, 0, stream>>>(scene, inc, hbuf, outH,
            n2eW, n2eb, t2eW, t2eb, roles, mean_ent, e_pre, ctxa, ctxi, cnt, list, rowrole, s);
        k_step_c<<<B_, 256, 0, stream>>>(e_pre, elng, elnb, gW1, gb1, gW2, gb2, outH, gatep, s);
        k_msg_gemm<<<dim3(D_/TN, MT), 256, 0, stream>>>(ctxa, ctxi, outH, gatep, list, cnt,
            rowrole, maW, miW, msW, maB, miB, msB, rolew, msgb, s);
        k_gru_gemm<<<dim3(G3_/TN, MT), 256, 0, stream>>>(msgb, hbuf, list, cnt,
            Wih, Whh, bih, bhh, gi, gh);
        k_gru_fin<<<BN_, 256, 0, stream>>>(gi, gh, list, cnt, ulng, ulnb, hbuf);
    }

    // epilogue: H = LN(gelu(LN(es + scene) @ eo_W^T + eo_b)); h_fin copy
    k_resln<<<B_*S_, 256, 0, stream>>>(outH, scene, rlng, rlnb);
    gemm_wt<<<dim3(D_/TN, (B_*S_ + TM - 1)/TM), 256, 0, stream>>>(outH, eoW, eoB, msgb, B_*S_, D_, D_);
    k_final<<<B_*S_ + BN_, 256, 0, stream>>>(msgb, eolng, eolnb, outH, hbuf, outh);
}

// Round 3
// 9695.717 us; speedup vs baseline: 5.1279x; 5.1279x over previous
//
#include <hip/hip_runtime.h>
#include <math.h>

#define B_   8
#define S_   64
#define N_   100
#define D_   1024
#define ND_  768
#define BN_  800
#define G3_  3072
#define G6_  6144
#define NB_EPRE 32

typedef __bf16 bf16x8 __attribute__((ext_vector_type(8)));
typedef float f32x4 __attribute__((ext_vector_type(4)));

#define MFMA __builtin_amdgcn_mfma_f32_16x16x32_bf16

static __device__ __forceinline__ float wave_sum(float v) {
    for (int off = 32; off > 0; off >>= 1) v += __shfl_down(v, off, 64);
    return v;
}

// All 256 threads must call; returns full-block sum to every thread.
static __device__ __forceinline__ float block_sum(float v) {
    __shared__ float red_[8];
    float w = wave_sum(v);
    int lane = threadIdx.x & 63, wid = threadIdx.x >> 6;
    __syncthreads();               // protect red_ reuse across calls
    if (lane == 0) red_[wid] = w;
    __syncthreads();
    float t = 0.f;
    for (int i = 0; i < 4; ++i) t += red_[i];
    return t;
}

static __device__ __forceinline__ float gelu_f(float x) {
    return 0.5f * x * (1.f + erff(x * 0.70710678118654752f));
}

static __device__ __forceinline__ unsigned short f2bf(float x) {
    union { float f; unsigned u; } v; v.f = x;
    unsigned r = v.u + 0x7FFFu + ((v.u >> 16) & 1u);
    return (unsigned short)(r >> 16);
}

// split: x ~= hi + lo, each bf16; residual error ~2^-17 relative
static __device__ __forceinline__ void f2bfs(float x, unsigned short& hi, unsigned short& lo) {
    unsigned short h = f2bf(x);
    union { unsigned u; float f; } vh; vh.u = (unsigned)h << 16;
    hi = h; lo = f2bf(x - vh.f);
}

static __device__ __forceinline__ void f2bfs4(float4 v, ushort4& h, ushort4& l) {
    f2bfs(v.x, h.x, l.x); f2bfs(v.y, h.y, l.y);
    f2bfs(v.z, h.z, l.z); f2bfs(v.w, h.w, l.w);
}

// ---------------------------------------------------------------------------
// fp32 -> split-bf16 2D convert (strided dst for the W_cat concat). cols%4==0.
// ---------------------------------------------------------------------------
__global__ __launch_bounds__(256) void k_f2bfsplit(
    const float* __restrict__ src, unsigned short* __restrict__ dhi,
    unsigned short* __restrict__ dlo, int rows, int cols, int ldd)
{
    size_t n = (size_t)rows * cols;
    size_t i = ((size_t)blockIdx.x * 256 + threadIdx.x) * 4;
    if (i >= n) return;
    int r = (int)(i / cols);
    int c = (int)(i - (size_t)r * cols);
    float4 v = *(const float4*)(src + i);
    ushort4 h, l; f2bfs4(v, h, l);
    *(ushort4*)(dhi + (size_t)r * ldd + c) = h;
    *(ushort4*)(dlo + (size_t)r * ldd + c) = l;
}

// ---------------------------------------------------------------------------
// Split MFMA GEMM: C[M,Nc] = (Ah+Al)[M,K] @ (Wh+Wl)[Nc,K]^T (+bias). fp32 out.
// 3-term: AhWh + AhWl + AlWh. TM=32, TN=128, K%64==0. Grid (Nc/128, ceil(M/32)).
// ---------------------------------------------------------------------------
__global__ __launch_bounds__(256) void k_mfma_nt(
    const unsigned short* __restrict__ Ah, const unsigned short* __restrict__ Al,
    const unsigned short* __restrict__ Wh, const unsigned short* __restrict__ Wl,
    const float* __restrict__ bias, float* __restrict__ C,
    int M, int Nc, int K)
{
    int m0 = blockIdx.y * 32; if (m0 >= M) return;
    int n0 = blockIdx.x * 128;
    __shared__ unsigned short sAh[32][72], sAl[32][72];
    __shared__ unsigned short sBh[128][72], sBl[128][72];
    int tid = threadIdx.x;
    int w = tid >> 6, l = tid & 63;
    int l15 = l & 15, q = l >> 4;
    int wn = w * 32;
    int arow = tid >> 3, achk = (tid & 7) * 8;
    f32x4 acc[2][2] = {};
    for (int k0 = 0; k0 < K; k0 += 64) {
        {
            int gm = m0 + arow;
            uint4 vh = make_uint4(0u,0u,0u,0u), vl = vh;
            if (gm < M) {
                vh = *(const uint4*)(Ah + (size_t)gm * K + k0 + achk);
                vl = *(const uint4*)(Al + (size_t)gm * K + k0 + achk);
            }
            *(uint4*)(&sAh[arow][achk]) = vh;
            *(uint4*)(&sAl[arow][achk]) = vl;
        }
        for (int i = 0; i < 4; ++i) {
            int r = arow + 32 * i;
            *(uint4*)(&sBh[r][achk]) = *(const uint4*)(Wh + (size_t)(n0 + r) * K + k0 + achk);
            *(uint4*)(&sBl[r][achk]) = *(const uint4*)(Wl + (size_t)(n0 + r) * K + k0 + achk);
        }
        __syncthreads();
#pragma unroll
        for (int ks = 0; ks < 64; ks += 32) {
            bf16x8 a0h = *(const bf16x8*)(&sAh[l15][ks + q*8]);
            bf16x8 a1h = *(const bf16x8*)(&sAh[16 + l15][ks + q*8]);
            bf16x8 a0l = *(const bf16x8*)(&sAl[l15][ks + q*8]);
            bf16x8 a1l = *(const bf16x8*)(&sAl[16 + l15][ks + q*8]);
            bf16x8 b0h = *(const bf16x8*)(&sBh[wn + l15][ks + q*8]);
            bf16x8 b1h = *(const bf16x8*)(&sBh[wn + 16 + l15][ks + q*8]);
            bf16x8 b0l = *(const bf16x8*)(&sBl[wn + l15][ks + q*8]);
            bf16x8 b1l = *(const bf16x8*)(&sBl[wn + 16 + l15][ks + q*8]);
            acc[0][0] = MFMA(a0h, b0h, acc[0][0], 0,0,0);
            acc[0][0] = MFMA(a0h, b0l, acc[0][0], 0,0,0);
            acc[0][0] = MFMA(a0l, b0h, acc[0][0], 0,0,0);
            acc[0][1] = MFMA(a0h, b1h, acc[0][1], 0,0,0);
            acc[0][1] = MFMA(a0h, b1l, acc[0][1], 0,0,0);
            acc[0][1] = MFMA(a0l, b1h, acc[0][1], 0,0,0);
            acc[1][0] = MFMA(a1h, b0h, acc[1][0], 0,0,0);
            acc[1][0] = MFMA(a1h, b0l, acc[1][0], 0,0,0);
            acc[1][0] = MFMA(a1l, b0h, acc[1][0], 0,0,0);
            acc[1][1] = MFMA(a1h, b1h, acc[1][1], 0,0,0);
            acc[1][1] = MFMA(a1h, b1l, acc[1][1], 0,0,0);
            acc[1][1] = MFMA(a1l, b1h, acc[1][1], 0,0,0);
        }
        __syncthreads();
    }
    for (int mi = 0; mi < 2; ++mi)
        for (int nj = 0; nj < 2; ++nj)
            for (int r = 0; r < 4; ++r) {
                int row = mi*16 + q*4 + r;
                int gm = m0 + row;
                int cl = wn + nj*16 + l15;
                if (gm < M) {
                    float bv = bias ? bias[n0 + cl] : 0.f;
                    C[(size_t)gm * Nc + n0 + cl] = acc[mi][nj][r] + bv;
                }
            }
}

// ---------------------------------------------------------------------------
// h0 = mask * (type_embed[type] + LN(P, name_ln)); writes fp32 h + split mirror
// ---------------------------------------------------------------------------
__global__ __launch_bounds__(256) void k_h0(
    const float* __restrict__ P, const int* __restrict__ etype,
    const int* __restrict__ emask, const float* __restrict__ temb,
    const float* __restrict__ g, const float* __restrict__ bt,
    float* __restrict__ h, unsigned short* __restrict__ hh, unsigned short* __restrict__ hl)
{
    int bn = blockIdx.x, tid = threadIdx.x;
    int t = etype[bn], mk = emask[bn];
    float x[4]; float lsum = 0.f;
    for (int k = 0; k < 4; ++k) { x[k] = P[(size_t)bn*D_ + tid + 256*k]; lsum += x[k]; }
    float mean = block_sum(lsum) * (1.f / D_);
    float lv = 0.f;
    for (int k = 0; k < 4; ++k) { float d = x[k] - mean; lv += d * d; }
    float inv = rsqrtf(block_sum(lv) * (1.f / D_) + 1e-5f);
    for (int k = 0; k < 4; ++k) {
        int d = tid + 256*k;
        float y = (x[k] - mean) * inv * g[d] + bt[d];
        float hv = mk ? (temb[(size_t)t*D_ + d] + y) : 0.f;
        h[(size_t)bn*D_ + d] = hv;
        unsigned short sh, sl; f2bfs(hv, sh, sl);
        hh[(size_t)bn*D_ + d] = sh;
        hl[(size_t)bn*D_ + d] = sl;
    }
}

// ---------------------------------------------------------------------------
// Step A: roles, wsum, mean_ent. Grid (B_, 4): block handles 256 d's.
// ---------------------------------------------------------------------------
__global__ __launch_bounds__(256) void k_step_a(
    const float* __restrict__ inc, const int* __restrict__ emask,
    const float* __restrict__ h, float* __restrict__ roles,
    float* __restrict__ mean_ent, int* __restrict__ cnt, int s)
{
    int b = blockIdx.x, tid = threadIdx.x;
    __shared__ float sroles[N_];
    float r = 0.f;
    if (tid < N_) {
        float iv = inc[((size_t)b*N_ + tid)*S_ + s];
        r = emask[b*N_ + tid] ? iv : 0.f;
        sroles[tid] = r;
        if (blockIdx.y == 0) roles[b*N_ + tid] = r;
    }
    float tot = block_sum(r);           // also orders sroles stores
    if (tid == 0 && b == 0 && blockIdx.y == 0) *cnt = 0;
    float inv = 1.f / fmaxf(tot, 1.f);
    int d = blockIdx.y * 256 + tid;
    float acc = 0.f;
    for (int n = 0; n < N_; ++n) acc += sroles[n] * h[((size_t)b*N_ + n)*D_ + d];
    mean_ent[b*D_ + d] = acc * inv;
}

// ---------------------------------------------------------------------------
// Step B: blocks [0,32): e_pre = n2e(mean_ent)+t2e(x_s)+biases (pre-LN)
//         blocks [32,832): per-(b,n) arc/int contexts + active compaction
// ---------------------------------------------------------------------------
__global__ __launch_bounds__(256) void k_step_b(
    const float* __restrict__ scene, const float* __restrict__ inc,
    const float* __restrict__ h, const float* __restrict__ esbuf,
    const float* __restrict__ n2eW, const float* __restrict__ n2eb,
    const float* __restrict__ t2eW, const float* __restrict__ t2eb,
    const float* __restrict__ roles, const float* __restrict__ mean_ent,
    float* __restrict__ e_pre, float* __restrict__ ctxa, float* __restrict__ ctxi,
    int* __restrict__ cnt, int* __restrict__ list, float* __restrict__ rowrole,
    int s)
{
    int tid = threadIdx.x;
    if (blockIdx.x < NB_EPRE) {
        __shared__ float sme[B_][D_ + 4];
        __shared__ float sxs[B_][D_ + 4];
        for (int i = tid; i < B_*D_; i += 256) {
            int b2 = i >> 10, j = i & (D_ - 1);
            sme[b2][j] = mean_ent[i];
            sxs[b2][j] = scene[((size_t)b2*S_ + s)*D_ + j];
        }
        __syncthreads();
        int il = tid >> 3, b = tid & 7;
        int i = blockIdx.x * 32 + il;
        float acc = n2eb[i] + t2eb[i];
        const float* wn = n2eW + (size_t)i * D_;
        const float* wt = t2eW + (size_t)i * D_;
        for (int j = 0; j < D_; j += 4) {
            float4 a = *(const float4*)(wn + j);
            float4 c = *(const float4*)(wt + j);
            acc += a.x*sme[b][j] + a.y*sme[b][j+1] + a.z*sme[b][j+2] + a.w*sme[b][j+3];
            acc += c.x*sxs[b][j] + c.y*sxs[b][j+1] + c.z*sxs[b][j+2] + c.w*sxs[b][j+3];
        }
        e_pre[b*D_ + i] = acc;
    } else {
        int m = blockIdx.x - NB_EPRE;
        int b = m / N_, n = m - b * N_;
        float r = roles[m];
        if (r <= 0.f) return;
        __shared__ int sidx, nwa, nwi;
        __shared__ float wav[S_]; __shared__ int wai[S_];
        __shared__ float wiv[N_]; __shared__ int wii[N_];
        if (tid == 0) { sidx = atomicAdd(cnt, 1); nwa = 0; nwi = 0; }
        __syncthreads();
        int idx = sidx;
        if (tid == 0) { list[idx] = m; rowrole[idx] = r; }
        float wa = 0.f;
        if (tid < s) {
            float denom = fmaxf((float)(s - 1), 1.f);
            float iv = inc[(size_t)m*S_ + tid];
            if (iv > 0.f) {
                wa = iv * r * expf(-1.f + (float)tid / denom);
                int p = atomicAdd(&nwa, 1);
                wav[p] = wa; wai[p] = tid;
            }
        }
        float denA = block_sum(wa);
        float wi = 0.f;
        if (tid < N_ && tid != n) {
            float rm = roles[b*N_ + tid];
            if (rm > 0.f) {
                wi = r * rm;
                int p = atomicAdd(&nwi, 1);
                wiv[p] = wi; wii[p] = tid;
            }
        }
        float denI = block_sum(wi);
        __syncthreads();
        float sclA = 1.f / fmaxf(denA, 1e-8f);
        float sclI = 1.f / fmaxf(denI, 1e-8f);
        int na = nwa, ni = nwi;
        for (int d = tid; d < D_; d += 256) {
            float a = 0.f;
            for (int j = 0; j < na; ++j) a += wav[j] * esbuf[((size_t)b*S_ + wai[j])*D_ + d];
            ctxa[(size_t)idx*D_ + d] = a * sclA;
            float c = 0.f;
            for (int j = 0; j < ni; ++j) c += wiv[j] * h[((size_t)b*N_ + wii[j])*D_ + d];
            ctxi[(size_t)idx*D_ + d] = c * sclI;
        }
    }
}

// ---------------------------------------------------------------------------
// Step C: e_s = LN(e_pre) -> esbuf[b,s,:]; gate[b,0..2] via softmax(MLP(e_s))
// ---------------------------------------------------------------------------
__global__ __launch_bounds__(256) void k_step_c(
    const float* __restrict__ e_pre, const float* __restrict__ elng, const float* __restrict__ elnb,
    const float* __restrict__ gW1, const float* __restrict__ gb1,
    const float* __restrict__ gW2, const float* __restrict__ gb2,
    float* __restrict__ esbuf, float* __restrict__ gate, int s)
{
    int b = blockIdx.x, tid = threadIdx.x;
    __shared__ float se[D_];
    float x[4]; float lsum = 0.f;
    for (int k = 0; k < 4; ++k) { x[k] = e_pre[b*D_ + tid + 256*k]; lsum += x[k]; }
    float mean = block_sum(lsum) * (1.f / D_);
    float lv = 0.f;
    for (int k = 0; k < 4; ++k) { float d = x[k] - mean; lv += d * d; }
    float inv = rsqrtf(block_sum(lv) * (1.f / D_) + 1e-5f);
    for (int k = 0; k < 4; ++k) {
        int d = tid + 256*k;
        float y = (x[k] - mean) * inv * elng[d] + elnb[d];
        se[d] = y;
        esbuf[((size_t)b*S_ + s)*D_ + d] = y;
    }
    __syncthreads();
    float acc = gb1[tid];
    const float* w1 = gW1 + (size_t)tid * D_;
    for (int j = 0; j < D_; j += 4) {
        float4 w = *(const float4*)(w1 + j);
        acc += w.x*se[j] + w.y*se[j+1] + w.z*se[j+2] + w.w*se[j+3];
    }
    float hg = gelu_f(acc);
    __shared__ float sh[256];
    sh[tid] = hg;
    float g[3];
    for (int c = 0; c < 3; ++c)
        g[c] = block_sum(gW2[c*256 + tid] * sh[tid]) + gb2[c];
    float mx = fmaxf(g[0], fmaxf(g[1], g[2]));
    float e0 = expf(g[0]-mx), e1 = expf(g[1]-mx), e2 = expf(g[2]-mx);
    float si = 1.f / (e0 + e1 + e2);
    if (tid == 0) { gate[b*4+0] = e0*si; gate[b*4+1] = e1*si; gate[b*4+2] = e2*si; }
}

// ---------------------------------------------------------------------------
// Build A' split [M,3072] = [g0*e_s | g1*ctxa | g2*ctxi] (compact rows)
// ---------------------------------------------------------------------------
__global__ __launch_bounds__(256) void k_build_msgA(
    const float* __restrict__ ctxa, const float* __restrict__ ctxi,
    const float* __restrict__ esbuf, const float* __restrict__ gate,
    const int* __restrict__ list, const int* __restrict__ cnt, int s,
    unsigned short* __restrict__ Ahi, unsigned short* __restrict__ Alo)
{
    int row = blockIdx.x;
    if (row >= *cnt) return;
    int b = list[row] / N_;
    float g0 = gate[b*4], g1 = (s > 0) ? gate[b*4+1] : 0.f, g2 = gate[b*4+2];
    int c = threadIdx.x * 4;
    float4 e = *(const float4*)(esbuf + ((size_t)b*S_ + s)*D_ + c);
    float4 a = *(const float4*)(ctxa + (size_t)row*D_ + c);
    float4 i4 = *(const float4*)(ctxi + (size_t)row*D_ + c);
    e.x *= g0; e.y *= g0; e.z *= g0; e.w *= g0;
    a.x *= g1; a.y *= g1; a.z *= g1; a.w *= g1;
    i4.x *= g2; i4.y *= g2; i4.z *= g2; i4.w *= g2;
    ushort4 h, l;
    f2bfs4(e, h, l);
    *(ushort4*)(Ahi + (size_t)row*G3_ + c) = h;
    *(ushort4*)(Alo + (size_t)row*G3_ + c) = l;
    f2bfs4(a, h, l);
    *(ushort4*)(Ahi + (size_t)row*G3_ + D_ + c) = h;
    *(ushort4*)(Alo + (size_t)row*G3_ + D_ + c) = l;
    f2bfs4(i4, h, l);
    *(ushort4*)(Ahi + (size_t)row*G3_ + 2*D_ + c) = h;
    *(ushort4*)(Alo + (size_t)row*G3_ + 2*D_ + c) = l;
}

// ---------------------------------------------------------------------------
// msg MFMA GEMM (split): msg[M,1024] = A'[M,3072] @ Wcat[1024,3072]^T + biases
// TM=32, TN=64. Grid (16, 25). Writes split msg planes.
// ---------------------------------------------------------------------------
__global__ __launch_bounds__(256) void k_mfma_msg(
    const unsigned short* __restrict__ Ahi, const unsigned short* __restrict__ Alo,
    const unsigned short* __restrict__ Wh, const unsigned short* __restrict__ Wl,
    const float* __restrict__ gate, const int* __restrict__ list,
    const int* __restrict__ cnt, const float* __restrict__ rowrole,
    const float* __restrict__ msB, const float* __restrict__ maB,
    const float* __restrict__ miB, const float* __restrict__ rolew,
    unsigned short* __restrict__ msgh, unsigned short* __restrict__ msgl, int s)
{
    int M = *cnt;
    int m0 = blockIdx.y * 32; if (m0 >= M) return;
    int n0 = blockIdx.x * 64;
    __shared__ unsigned short sAh[32][72], sAl[32][72];
    __shared__ unsigned short sBh[64][72], sBl[64][72];
    __shared__ float sg0[32], sg1[32], sg2[32], srr[32];
    int tid = threadIdx.x;
    if (tid < 32) {
        int gm = m0 + tid;
        float g0 = 0.f, g1 = 0.f, g2 = 0.f, rv = 0.f;
        if (gm < M) {
            int b = list[gm] / N_;
            g0 = gate[b*4]; g1 = (s > 0) ? gate[b*4+1] : 0.f; g2 = gate[b*4+2];
            rv = rowrole[gm];
        }
        sg0[tid] = g0; sg1[tid] = g1; sg2[tid] = g2; srr[tid] = rv;
    }
    int w = tid >> 6, l = tid & 63;
    int l15 = l & 15, q = l >> 4;
    int wm = (w & 1) * 16, wn = (w >> 1) * 32;
    int arow = tid >> 3, achk = (tid & 7) * 8;
    f32x4 acc[2] = {};
    for (int k0 = 0; k0 < G3_; k0 += 64) {
        {
            int gm = m0 + arow;
            uint4 vh = make_uint4(0u,0u,0u,0u), vl = vh;
            if (gm < M) {
                vh = *(const uint4*)(Ahi + (size_t)gm * G3_ + k0 + achk);
                vl = *(const uint4*)(Alo + (size_t)gm * G3_ + k0 + achk);
            }
            *(uint4*)(&sAh[arow][achk]) = vh;
            *(uint4*)(&sAl[arow][achk]) = vl;
        }
        *(uint4*)(&sBh[arow][achk])      = *(const uint4*)(Wh + (size_t)(n0 + arow) * G3_ + k0 + achk);
        *(uint4*)(&sBh[arow + 32][achk]) = *(const uint4*)(Wh + (size_t)(n0 + arow + 32) * G3_ + k0 + achk);
        *(uint4*)(&sBl[arow][achk])      = *(const uint4*)(Wl + (size_t)(n0 + arow) * G3_ + k0 + achk);
        *(uint4*)(&sBl[arow + 32][achk]) = *(const uint4*)(Wl + (size_t)(n0 + arow + 32) * G3_ + k0 + achk);
        __syncthreads();
#pragma unroll
        for (int ks = 0; ks < 64; ks += 32) {
            bf16x8 ah = *(const bf16x8*)(&sAh[wm + l15][ks + q*8]);
            bf16x8 al = *(const bf16x8*)(&sAl[wm + l15][ks + q*8]);
            bf16x8 b0h = *(const bf16x8*)(&sBh[wn + l15][ks + q*8]);
            bf16x8 b1h = *(const bf16x8*)(&sBh[wn + 16 + l15][ks + q*8]);
            bf16x8 b0l = *(const bf16x8*)(&sBl[wn + l15][ks + q*8]);
            bf16x8 b1l = *(const bf16x8*)(&sBl[wn + 16 + l15][ks + q*8]);
            acc[0] = MFMA(ah, b0h, acc[0], 0,0,0);
            acc[0] = MFMA(ah, b0l, acc[0], 0,0,0);
            acc[0] = MFMA(al, b0h, acc[0], 0,0,0);
            acc[1] = MFMA(ah, b1h, acc[1], 0,0,0);
            acc[1] = MFMA(ah, b1l, acc[1], 0,0,0);
            acc[1] = MFMA(al, b1h, acc[1], 0,0,0);
        }
        __syncthreads();
    }
    for (int j = 0; j < 2; ++j)
        for (int r = 0; r < 4; ++r) {
            int row = wm + q*4 + r;
            int gm = m0 + row;
            if (gm < M) {
                int d = n0 + wn + j*16 + l15;
                float v = acc[j][r] + sg0[row]*msB[d] + sg1[row]*maB[d]
                        + sg2[row]*miB[d] + srr[row]*rolew[d];
                unsigned short sh, sl; f2bfs(v, sh, sl);
                msgh[(size_t)gm*D_ + d] = sh;
                msgl[(size_t)gm*D_ + d] = sl;
            }
        }
}

// ---------------------------------------------------------------------------
// GRU MFMA GEMM (split): gig[M,6144]. cols<3072: msg@Wih^T+bih; else h(gather)@Whh^T+bhh
// TM=32, TN=128. Grid (48, 25).
// ---------------------------------------------------------------------------
__global__ __launch_bounds__(256) void k_mfma_gru(
    const unsigned short* __restrict__ msgh, const unsigned short* __restrict__ msgl,
    const unsigned short* __restrict__ hh, const unsigned short* __restrict__ hl,
    const int* __restrict__ list, const int* __restrict__ cnt,
    const unsigned short* __restrict__ Wihh, const unsigned short* __restrict__ Wihl,
    const unsigned short* __restrict__ Whhh, const unsigned short* __restrict__ Whhl,
    const float* __restrict__ bih, const float* __restrict__ bhh,
    float* __restrict__ gig)
{
    int M = *cnt;
    int m0 = blockIdx.y * 32; if (m0 >= M) return;
    int n0 = blockIdx.x * 128;
    bool second = (n0 >= G3_);
    int nloc = second ? (n0 - G3_) : n0;
    const unsigned short* Wh = second ? Whhh : Wihh;
    const unsigned short* Wl = second ? Whhl : Wihl;
    const float* bias = second ? (bhh + nloc) : (bih + nloc);
    __shared__ unsigned short sAh[32][72], sAl[32][72];
    __shared__ unsigned short sBh[128][72], sBl[128][72];
    __shared__ int slist[32];
    int tid = threadIdx.x;
    if (tid < 32) {
        int gm = m0 + tid;
        slist[tid] = (gm < M) ? list[gm] : 0;
    }
    __syncthreads();
    int w = tid >> 6, l = tid & 63;
    int l15 = l & 15, q = l >> 4;
    int wn = w * 32;
    int arow = tid >> 3, achk = (tid & 7) * 8;
    f32x4 acc[2][2] = {};
    for (int k0 = 0; k0 < D_; k0 += 64) {
        {
            int gm = m0 + arow;
            uint4 vh = make_uint4(0u,0u,0u,0u), vl = vh;
            if (gm < M) {
                if (second) {
                    const unsigned short* s1 = hh + (size_t)slist[arow] * D_;
                    const unsigned short* s2 = hl + (size_t)slist[arow] * D_;
                    vh = *(const uint4*)(s1 + k0 + achk);
                    vl = *(const uint4*)(s2 + k0 + achk);
                } else {
                    vh = *(const uint4*)(msgh + (size_t)gm * D_ + k0 + achk);
                    vl = *(const uint4*)(msgl + (size_t)gm * D_ + k0 + achk);
                }
            }
            *(uint4*)(&sAh[arow][achk]) = vh;
            *(uint4*)(&sAl[arow][achk]) = vl;
        }
        for (int i = 0; i < 4; ++i) {
            int r = arow + 32 * i;
            *(uint4*)(&sBh[r][achk]) = *(const uint4*)(Wh + (size_t)(nloc + r) * D_ + k0 + achk);
            *(uint4*)(&sBl[r][achk]) = *(const uint4*)(Wl + (size_t)(nloc + r) * D_ + k0 + achk);
        }
        __syncthreads();
#pragma unroll
        for (int ks = 0; ks < 64; ks += 32) {
            bf16x8 a0h = *(const bf16x8*)(&sAh[l15][ks + q*8]);
            bf16x8 a1h = *(const bf16x8*)(&sAh[16 + l15][ks + q*8]);
            bf16x8 a0l = *(const bf16x8*)(&sAl[l15][ks + q*8]);
            bf16x8 a1l = *(const bf16x8*)(&sAl[16 + l15][ks + q*8]);
            bf16x8 b0h = *(const bf16x8*)(&sBh[wn + l15][ks + q*8]);
            bf16x8 b1h = *(const bf16x8*)(&sBh[wn + 16 + l15][ks + q*8]);
            bf16x8 b0l = *(const bf16x8*)(&sBl[wn + l15][ks + q*8]);
            bf16x8 b1l = *(const bf16x8*)(&sBl[wn + 16 + l15][ks + q*8]);
            acc[0][0] = MFMA(a0h, b0h, acc[0][0], 0,0,0);
            acc[0][0] = MFMA(a0h, b0l, acc[0][0], 0,0,0);
            acc[0][0] = MFMA(a0l, b0h, acc[0][0], 0,0,0);
            acc[0][1] = MFMA(a0h, b1h, acc[0][1], 0,0,0);
            acc[0][1] = MFMA(a0h, b1l, acc[0][1], 0,0,0);
            acc[0][1] = MFMA(a0l, b1h, acc[0][1], 0,0,0);
            acc[1][0] = MFMA(a1h, b0h, acc[1][0], 0,0,0);
            acc[1][0] = MFMA(a1h, b0l, acc[1][0], 0,0,0);
            acc[1][0] = MFMA(a1l, b0h, acc[1][0], 0,0,0);
            acc[1][1] = MFMA(a1h, b1h, acc[1][1], 0,0,0);
            acc[1][1] = MFMA(a1h, b1l, acc[1][1], 0,0,0);
            acc[1][1] = MFMA(a1l, b1h, acc[1][1], 0,0,0);
        }
        __syncthreads();
    }
    for (int mi = 0; mi < 2; ++mi)
        for (int nj = 0; nj < 2; ++nj)
            for (int r = 0; r < 4; ++r) {
                int row = mi*16 + q*4 + r;
                int gm = m0 + row;
                if (gm < M) {
                    int cl = wn + nj*16 + l15;
                    gig[(size_t)gm * G6_ + n0 + cl] = acc[mi][nj][r] + bias[cl];
                }
            }
}

// ---------------------------------------------------------------------------
// Step F: GRU gates + LN + clip, masked write into h (+split mirror).
// gig layout: [row][0:3072]=gi, [row][3072:6144]=gh
// ---------------------------------------------------------------------------
__global__ __launch_bounds__(256) void k_gru_fin(
    const float* __restrict__ gig,
    const int* __restrict__ list, const int* __restrict__ cnt,
    const float* __restrict__ ulng, const float* __restrict__ ulnb,
    float* __restrict__ h, unsigned short* __restrict__ hh, unsigned short* __restrict__ hl)
{
    int row = blockIdx.x;
    if (row >= *cnt) return;
    int bn = list[row];
    int tid = threadIdx.x;
    const float* gi = gig + (size_t)row * G6_;
    const float* gh = gi + G3_;
    float u[4]; float lsum = 0.f;
    for (int k = 0; k < 4; ++k) {
        int d = tid + 256*k;
        float ir = gi[d], iz = gi[D_ + d], in_ = gi[2*D_ + d];
        float hr = gh[d], hz = gh[D_ + d], hn = gh[2*D_ + d];
        float hv = h[(size_t)bn*D_ + d];
        float r = 1.f / (1.f + expf(-(ir + hr)));
        float z = 1.f / (1.f + expf(-(iz + hz)));
        float nn = tanhf(in_ + r * hn);
        u[k] = (1.f - z) * nn + z * hv;
        lsum += u[k];
    }
    float mean = block_sum(lsum) * (1.f / D_);
    float lv = 0.f;
    for (int k = 0; k < 4; ++k) { float d = u[k] - mean; lv += d * d; }
    float inv = rsqrtf(block_sum(lv) * (1.f / D_) + 1e-5f);
    for (int k = 0; k < 4; ++k) {
        int d = tid + 256*k;
        float y = (u[k] - mean) * inv * ulng[d] + ulnb[d];
        y = fminf(fmaxf(y, -50.f), 50.f);
        h[(size_t)bn*D_ + d] = y;
        unsigned short sh, sl; f2bfs(y, sh, sl);
        hh[(size_t)bn*D_ + d] = sh;
        hl[(size_t)bn*D_ + d] = sl;
    }
}

// ---------------------------------------------------------------------------
// Final: buf = LN(buf + scene, res_ln) in-place; also split copy to H planes.
// ---------------------------------------------------------------------------
__global__ __launch_bounds__(256) void k_resln(
    float* __restrict__ buf, const float* __restrict__ scene,
    const float* __restrict__ g, const float* __restrict__ bt,
    unsigned short* __restrict__ Hh, unsigned short* __restrict__ Hl)
{
    size_t row = blockIdx.x;
    int tid = threadIdx.x;
    float x[4]; float lsum = 0.f;
    for (int k = 0; k < 4; ++k) {
        int d = tid + 256*k;
        x[k] = buf[row*D_ + d] + scene[row*D_ + d];
        lsum += x[k];
    }
    float mean = block_sum(lsum) * (1.f / D_);
    float lv = 0.f;
    for (int k = 0; k < 4; ++k) { float d = x[k] - mean; lv += d * d; }
    float inv = rsqrtf(block_sum(lv) * (1.f / D_) + 1e-5f);
    for (int k = 0; k < 4; ++k) {
        int d = tid + 256*k;
        float y = (x[k] - mean) * inv * g[d] + bt[d];
        buf[row*D_ + d] = y;
        unsigned short sh, sl; f2bfs(y, sh, sl);
        Hh[row*D_ + d] = sh;
        Hl[row*D_ + d] = sl;
    }
}

// ---------------------------------------------------------------------------
// Final: H = LN(gelu(G), eo_ln); plus h_fin copy blocks.
// ---------------------------------------------------------------------------
__global__ __launch_bounds__(256) void k_final(
    const float* __restrict__ G, const float* __restrict__ g, const float* __restrict__ bt,
    float* __restrict__ outH, const float* __restrict__ h, float* __restrict__ outh)
{
    int tid = threadIdx.x;
    if (blockIdx.x < B_*S_) {
        size_t row = blockIdx.x;
        float x[4]; float lsum = 0.f;
        for (int k = 0; k < 4; ++k) {
            x[k] = gelu_f(G[row*D_ + tid + 256*k]);
            lsum += x[k];
        }
        float mean = block_sum(lsum) * (1.f / D_);
        float lv = 0.f;
        for (int k = 0; k < 4; ++k) { float d = x[k] - mean; lv += d * d; }
        float inv = rsqrtf(block_sum(lv) * (1.f / D_) + 1e-5f);
        for (int k = 0; k < 4; ++k) {
            int d = tid + 256*k;
            outH[row*D_ + d] = (x[k] - mean) * inv * g[d] + bt[d];
        }
    } else {
        size_t bn = blockIdx.x - B_*S_;
        for (int d = tid; d < D_; d += 256)
            outh[bn*D_ + d] = h[bn*D_ + d];
    }
}

// ---------------------------------------------------------------------------
extern "C" void kernel_launch(void* const* d_in, const int* in_sizes, int n_in,
                              void* d_out, int out_size, void* d_ws, size_t ws_size,
                              hipStream_t stream)
{
    const float* scene = (const float*)d_in[0];
    const float* inc   = (const float*)d_in[1];
    const int*   etype = (const int*)d_in[3];
    const int*   emask = (const int*)d_in[4];
    const float* nemb  = (const float*)d_in[5];
    const float* temb  = (const float*)d_in[6];
    const float* nameW = (const float*)d_in[7];
    const float* nlg   = (const float*)d_in[8];
    const float* nlb   = (const float*)d_in[9];
    const float* n2eW  = (const float*)d_in[10];
    const float* n2eb  = (const float*)d_in[11];
    const float* t2eW  = (const float*)d_in[12];
    const float* t2eb  = (const float*)d_in[13];
    const float* elng  = (const float*)d_in[14];
    const float* elnb  = (const float*)d_in[15];
    const float* gW1   = (const float*)d_in[16];
    const float* gb1   = (const float*)d_in[17];
    const float* gW2   = (const float*)d_in[18];
    const float* gb2   = (const float*)d_in[19];
    const float* msW   = (const float*)d_in[20];
    const float* msB   = (const float*)d_in[21];
    const float* maW   = (const float*)d_in[22];
    const float* maB   = (const float*)d_in[23];
    const float* miW   = (const float*)d_in[24];
    const float* miB   = (const float*)d_in[25];
    const float* rolew = (const float*)d_in[26];
    const float* Wih   = (const float*)d_in[27];
    const float* Whh   = (const float*)d_in[28];
    const float* bih   = (const float*)d_in[29];
    const float* bhh   = (const float*)d_in[30];
    const float* ulng  = (const float*)d_in[31];
    const float* ulnb  = (const float*)d_in[32];
    const float* eoW   = (const float*)d_in[33];
    const float* eoB   = (const float*)d_in[34];
    const float* eolng = (const float*)d_in[35];
    const float* eolnb = (const float*)d_in[36];
    const float* rlng  = (const float*)d_in[37];
    const float* rlnb  = (const float*)d_in[38];

    float* outH = (float*)d_out;                    // [B,S,D] — doubles as ebuf
    float* outh = outH + (size_t)B_*S_*D_;          // [B,N,D] h_fin

    float* W = (float*)d_ws;
    size_t o = 0;
    float* roles    = W + o; o += BN_;
    float* mean_ent = W + o; o += (size_t)B_*D_;
    float* e_pre    = W + o; o += (size_t)B_*D_;
    float* gatep    = W + o; o += B_*4;
    float* rowrole  = W + o; o += BN_;
    int*   cnt      = (int*)(W + o); o += 4;
    int*   list     = (int*)(W + o); o += BN_;
    float* ctxa     = W + o; o += (size_t)BN_*D_;
    float* ctxi     = W + o; o += (size_t)BN_*D_;
    float* hbuf     = W + o; o += (size_t)BN_*D_;
    float* gig      = W + o; o += (size_t)BN_*G6_;  // also P (init) and G (final)
    unsigned short* U = (unsigned short*)(W + o);
    size_t uo = 0;
    unsigned short* Ahi   = U + uo; uo += (size_t)BN_*G3_;   // also H-planes (epilogue)
    unsigned short* Alo   = U + uo; uo += (size_t)BN_*G3_;
    unsigned short* msgh  = U + uo; uo += (size_t)BN_*D_;
    unsigned short* msgl  = U + uo; uo += (size_t)BN_*D_;
    unsigned short* hh    = U + uo; uo += (size_t)BN_*D_;
    unsigned short* hl    = U + uo; uo += (size_t)BN_*D_;
    unsigned short* Wcath = U + uo; uo += (size_t)D_*G3_;
    unsigned short* Wcatl = U + uo; uo += (size_t)D_*G3_;
    unsigned short* Wihh  = U + uo; uo += (size_t)G3_*D_;
    unsigned short* Wihl  = U + uo; uo += (size_t)G3_*D_;
    unsigned short* Whhh  = U + uo; uo += (size_t)G3_*D_;
    unsigned short* Whhl  = U + uo; uo += (size_t)G3_*D_;
    unsigned short* eoWh  = U + uo; uo += (size_t)D_*D_;
    unsigned short* eoWl  = U + uo; uo += (size_t)D_*D_;
    unsigned short* nWh   = U + uo; uo += (size_t)D_*ND_;
    unsigned short* nWl   = U + uo; uo += (size_t)D_*ND_;
    unsigned short* nEh   = U + uo; uo += (size_t)BN_*ND_;
    unsigned short* nEl   = U + uo; uo += (size_t)BN_*ND_;
    // H-planes for the epilogue eo-GEMM alias Ahi/Alo (loop is done by then)
    unsigned short* Hh = Ahi;
    unsigned short* Hl = Alo;

    // ---- weight conversion (per call; inputs restored each timed call) ----
    #define CVT(src, dh, dl, r, c, ld) \
        k_f2bfsplit<<<(((size_t)(r)*(c)/4 + 255)/256), 256, 0, stream>>>(src, dh, dl, r, c, ld)
    CVT(Wih,   Wihh, Wihl,            G3_, D_,  D_);
    CVT(Whh,   Whhh, Whhl,            G3_, D_,  D_);
    CVT(msW,   Wcath + 0,    Wcatl + 0,    D_, D_, G3_);
    CVT(maW,   Wcath + D_,   Wcatl + D_,   D_, D_, G3_);
    CVT(miW,   Wcath + 2*D_, Wcatl + 2*D_, D_, D_, G3_);
    CVT(nameW, nWh, nWl,              D_,  ND_, ND_);
    CVT(nemb,  nEh, nEl,              BN_, ND_, ND_);
    CVT(eoW,   eoWh, eoWl,            D_,  D_,  D_);
    #undef CVT

    // init: P = name_embs @ name_W^T (split MFMA) ; h0 (+ split mirror)
    k_mfma_nt<<<dim3(D_/128, (BN_+31)/32), 256, 0, stream>>>(
        nEh, nEl, nWh, nWl, nullptr, gig, BN_, D_, ND_);
    k_h0<<<BN_, 256, 0, stream>>>(gig, etype, emask, temb, nlg, nlb, hbuf, hh, hl);

    for (int s = 0; s < S_; ++s) {
        k_step_a<<<dim3(B_, 4), 256, 0, stream>>>(inc, emask, hbuf, roles, mean_ent, cnt, s);
        k_step_b<<<NB_EPRE + BN_, 256, 0, stream>>>(scene, inc, hbuf, outH,
            n2eW, n2eb, t2eW, t2eb, roles, mean_ent, e_pre, ctxa, ctxi, cnt, list, rowrole, s);
        k_step_c<<<B_, 256, 0, stream>>>(e_pre, elng, elnb, gW1, gb1, gW2, gb2, outH, gatep, s);
        k_build_msgA<<<BN_, 256, 0, stream>>>(ctxa, ctxi, outH, gatep, list, cnt, s, Ahi, Alo);
        k_mfma_msg<<<dim3(16, (BN_+31)/32), 256, 0, stream>>>(Ahi, Alo, Wcath, Wcatl,
            gatep, list, cnt, rowrole, msB, maB, miB, rolew, msgh, msgl, s);
        k_mfma_gru<<<dim3(48, (BN_+31)/32), 256, 0, stream>>>(msgh, msgl, hh, hl, list, cnt,
            Wihh, Wihl, Whhh, Whhl, bih, bhh, gig);
        k_gru_fin<<<BN_, 256, 0, stream>>>(gig, list, cnt, ulng, ulnb, hbuf, hh, hl);
    }

    // epilogue: H = LN(gelu(LN(es + scene) @ eo_W^T + eo_b)); h_fin copy
    k_resln<<<B_*S_, 256, 0, stream>>>(outH, scene, rlng, rlnb, Hh, Hl);
    k_mfma_nt<<<dim3(D_/128, (B_*S_+31)/32), 256, 0, stream>>>(
        Hh, Hl, eoWh, eoWl, eoB, gig, B_*S_, D_, D_);
    k_final<<<B_*S_ + BN_, 256, 0, stream>>>(gig, eolng, eolnb, outH, hbuf, outh);
}